// Round 6
// baseline (697.398 us; speedup 1.0000x reference)
//
#include <hip/hip_runtime.h>
#include <hip/hip_bf16.h>
#include <cstdint>
#include <cstddef>

typedef short bf16x8 __attribute__((ext_vector_type(8)));
typedef float f32x4 __attribute__((ext_vector_type(4)));

static __device__ __forceinline__ unsigned short f2bf(float f) {
    union { float f; uint32_t u; } c; c.f = f;
    uint32_t r = c.u + 0x7FFFu + ((c.u >> 16) & 1u);
    return (unsigned short)(r >> 16);
}
static __device__ __forceinline__ float bf2f_lo(uint32_t w) {
    union { uint32_t u; float f; } c; c.u = w << 16; return c.f;
}
static __device__ __forceinline__ float bf2f_hi(uint32_t w) {
    union { uint32_t u; float f; } c; c.u = w & 0xffff0000u; return c.f;
}
static __device__ __forceinline__ float fast_tanh(float x) {
    float e = __expf(2.0f * x);
    return 1.0f - 2.0f / (e + 1.0f);
}
static __device__ __forceinline__ float softplus_f(float x) {
    return fmaxf(x, 0.0f) + log1pf(__expf(-fabsf(x)));
}

#define GLOAD_LDS16(g, l) \
    __builtin_amdgcn_global_load_lds((const __attribute__((address_space(1))) void*)(g), \
                                     (__attribute__((address_space(3))) void*)(l), 16, 0, 0)

// ---------------- f32 -> bf16 conversion, 5 segments in one launch ----------
__global__ __launch_bounds__(256) void k_convert(
    const float* __restrict__ s0, const float* __restrict__ s1,
    const float* __restrict__ s2, const float* __restrict__ s3,
    const float* __restrict__ s4,
    unsigned short* __restrict__ d0, unsigned short* __restrict__ d1,
    unsigned short* __restrict__ d2, unsigned short* __restrict__ d3,
    unsigned short* __restrict__ d4,
    int n0, int n1, int n2, int n3, int n4)
{
    int i = blockIdx.x * 256 + threadIdx.x; // float4 index
    int c0 = n0 >> 2, c1 = c0 + (n1 >> 2), c2 = c1 + (n2 >> 2),
        c3 = c2 + (n3 >> 2), c4 = c3 + (n4 >> 2);
    if (i >= c4) return;
    const float* s; unsigned short* d; int j;
    if (i < c0)      { s = s0; d = d0; j = i; }
    else if (i < c1) { s = s1; d = d1; j = i - c0; }
    else if (i < c2) { s = s2; d = d2; j = i - c1; }
    else if (i < c3) { s = s3; d = d3; j = i - c2; }
    else             { s = s4; d = d4; j = i - c3; }
    float4 v = reinterpret_cast<const float4*>(s)[j];
    ushort4 o;
    o.x = f2bf(v.x); o.y = f2bf(v.y); o.z = f2bf(v.z); o.w = f2bf(v.w);
    reinterpret_cast<ushort4*>(d)[j] = o;
}

// ---------------- projection GEMM: out[m,f] = sum_d A[m,d]*W[f,d] + bias[f] --
__global__ __launch_bounds__(256) void k_proj(
    const unsigned short* __restrict__ A,   // [M][512] bf16
    const unsigned short* __restrict__ W,   // [1024][512] bf16
    const float* __restrict__ bias,         // [1024]
    float* __restrict__ out)                // [M][1024] f32
{
    __shared__ unsigned short As[32 * 512];
    const int tid = threadIdx.x;
    const int m0 = blockIdx.x * 32;
    const int c0 = blockIdx.y * 128;
    {
        int row = tid >> 3;
        const unsigned short* src = A + (size_t)(m0 + row) * 512;
        unsigned int base = row * 1024;
        unsigned int sw = (row & 7) << 4;
        #pragma unroll
        for (int c = 0; c < 8; ++c) {
            int col = (tid & 7) * 8 + c * 64;
            bf16x8 v = *reinterpret_cast<const bf16x8*>(src + col);
            *reinterpret_cast<bf16x8*>(
                reinterpret_cast<char*>(As) + ((base + col * 2) ^ sw)) = v;
        }
    }
    __syncthreads();
    const int w = tid >> 6, l = tid & 63;
    const int lr = l & 15, lkb = (l >> 4) * 8;
    f32x4 acc[2][2] = {};
    const int colbase = c0 + w * 32;
    const unsigned short* Wb = W + (size_t)(colbase + lr) * 512 + lkb;
    const unsigned int sw = (lr & 7) << 4;
    for (int ks = 0; ks < 16; ++ks) {
        unsigned int kb = (ks * 32 + lkb) * 2;
        bf16x8 a0 = *reinterpret_cast<const bf16x8*>(
            reinterpret_cast<const char*>(As) + ((lr * 1024 + kb) ^ sw));
        bf16x8 a1 = *reinterpret_cast<const bf16x8*>(
            reinterpret_cast<const char*>(As) + (((16 + lr) * 1024 + kb) ^ sw));
        #pragma unroll
        for (int nf = 0; nf < 2; ++nf) {
            bf16x8 b = *reinterpret_cast<const bf16x8*>(Wb + nf * 16 * 512 + ks * 32);
            acc[0][nf] = __builtin_amdgcn_mfma_f32_16x16x32_bf16(a0, b, acc[0][nf], 0, 0, 0);
            acc[1][nf] = __builtin_amdgcn_mfma_f32_16x16x32_bf16(a1, b, acc[1][nf], 0, 0, 0);
        }
    }
    const int qr = (l >> 4) * 4;
    #pragma unroll
    for (int nf = 0; nf < 2; ++nf) {
        int col = colbase + nf * 16 + lr;
        float bv = bias[col];
        #pragma unroll
        for (int mf = 0; mf < 2; ++mf)
            #pragma unroll
            for (int r = 0; r < 4; ++r)
                out[(size_t)(m0 + mf * 16 + qr + r) * 1024 + col] = acc[mf][nf][r] + bv;
    }
}

// ---------------- A = tanh(enc+dec) -> bf16, interleaved into out -----------
// Row r of out (4096 B): bytes [0,2048) hold A[r][0..1023] bf16.
__global__ __launch_bounds__(256) void k_tanhA(
    const float* __restrict__ enc_f,   // [1600][1024]
    const float* __restrict__ dec_f,   // [320][1024]
    char* __restrict__ outb)
{
    const int NG = 128000 * 128;       // 16B groups
    for (int g = blockIdx.x * 256 + threadIdx.x; g < NG; g += gridDim.x * 256) {
        int row = g >> 7, c8 = g & 127;
        int bt = row / 80;
        int u = row - bt * 80;
        int b = bt / 400;
        const float* ep = enc_f + (size_t)bt * 1024 + c8 * 8;
        const float* dp = dec_f + (size_t)(b * 80 + u) * 1024 + c8 * 8;
        float4 e0 = *(const float4*)ep, e1 = *(const float4*)(ep + 4);
        float4 f0 = *(const float4*)dp, f1 = *(const float4*)(dp + 4);
        uint4 pk;
        pk.x = (uint32_t)f2bf(fast_tanh(e0.x + f0.x)) | ((uint32_t)f2bf(fast_tanh(e0.y + f0.y)) << 16);
        pk.y = (uint32_t)f2bf(fast_tanh(e0.z + f0.z)) | ((uint32_t)f2bf(fast_tanh(e0.w + f0.w)) << 16);
        pk.z = (uint32_t)f2bf(fast_tanh(e1.x + f1.x)) | ((uint32_t)f2bf(fast_tanh(e1.y + f1.y)) << 16);
        pk.w = (uint32_t)f2bf(fast_tanh(e1.z + f1.z)) | ((uint32_t)f2bf(fast_tanh(e1.w + f1.w)) << 16);
        *(uint4*)(outb + (size_t)row * 4096 + c8 * 16) = pk;
    }
}

// ---------------- main GEMM: logits = A @ Wfc^T + bias (bf16 out) -----------
// 256x256 tile, BK=64, 512 thr (8 waves: wm 2 x wn 4), 2x64KB LDS dbuf,
// 8-phase-style schedule: per K-tile 4 phases {ds_read subtile -> raw
// s_barrier -> setprio(1) 16 MFMA setprio(0)}, all 8 global_load_lds for
// tile t+1 issued at phase 0 (latency hidden under 3 phases of MFMA),
// single vmcnt(0)+raw barrier at the tile boundary (loads span phases,
// no per-barrier drain). XOR-swizzled LDS, pre-swizzled gload sources.
__global__ __launch_bounds__(512, 1) void k_gemm(
    const unsigned short* __restrict__ Wfc,   // [1024][1024] bf16
    const float* __restrict__ bfc,            // [1024]
    char* __restrict__ outb)                  // A in [0,2048), logits out [2048,4096)
{
    extern __shared__ char smem[];            // 2 x (32KB A + 32KB B)
    const int tid = threadIdx.x;
    const int w = tid >> 6, l = tid & 63;
    const int lr = l & 15, q = l >> 4;
    const int wm = w >> 2, wn = w & 3;

    // grid 2000 = 8 XCDs x 250; within XCD: np fastest (4 N-panels share A)
    const int bid = (int)blockIdx.x;
    const int g = (bid & 7) * 250 + (bid >> 3);
    const size_t R0 = (size_t)(g >> 2) * 256;
    const int n0 = (g & 3) * 256;

    // staging source (pre-swizzled): dest d = tid*16 + i*8192 (linear),
    // logical L = d ^ (((d>>7)&7)<<4); row = L>>7 = tid>>3 + i*64, kb = L&127
    const unsigned kb0 = (unsigned)(((tid & 7) * 16) ^ (((tid >> 3) & 7) << 4));
    const int row0 = tid >> 3;
    const char* sA = outb + (R0 + row0) * 4096 + kb0;
    const char* sB = (const char*)Wfc + (size_t)(n0 + row0) * 2048 + kb0;

#define STAGE(dbuf, koff) do { \
    const char* _a = sA + (koff); \
    const char* _b = sB + (koff); \
    char* _d = smem + (dbuf) * 65536 + tid * 16; \
    GLOAD_LDS16(_a,          _d);          \
    GLOAD_LDS16(_a + 262144, _d + 8192);   \
    GLOAD_LDS16(_a + 524288, _d + 16384);  \
    GLOAD_LDS16(_a + 786432, _d + 24576);  \
    GLOAD_LDS16(_b,          _d + 32768);  \
    GLOAD_LDS16(_b + 131072, _d + 40960);  \
    GLOAD_LDS16(_b + 262144, _d + 49152);  \
    GLOAD_LDS16(_b + 393216, _d + 57344);  \
} while (0)

    // fragment read offsets
    const unsigned key = (unsigned)((lr & 7) << 4);
    const unsigned kx0 = (unsigned)(q * 16) ^ key;
    const unsigned kx1 = (unsigned)(q * 16 + 64) ^ key;
    const unsigned abase = (unsigned)((wm * 128 + lr) * 128);           // + h*8192 + mf*2048
    const unsigned bbase = (unsigned)(32768 + (wn * 64 + lr) * 128);    // + nf*2048

    f32x4 acc[8][4] = {};
    bf16x8 af[4][2], bf[4][2];

    // prologue: stage tile 0 into buf 0
    STAGE(0, 0);
    asm volatile("s_waitcnt vmcnt(0)" ::: "memory");
    __builtin_amdgcn_s_barrier();
    __builtin_amdgcn_sched_barrier(0);

#define LDA(h) do { \
    _Pragma("unroll") \
    for (int mf = 0; mf < 4; ++mf) { \
        const char* _p = smem + cb + abase + (h) * 8192 + mf * 2048; \
        af[mf][0] = *(const bf16x8*)(_p + kx0); \
        af[mf][1] = *(const bf16x8*)(_p + kx1); \
    } } while (0)
#define LDB(gg) do { \
    _Pragma("unroll") \
    for (int j = 0; j < 2; ++j) { \
        const char* _p = smem + cb + bbase + ((gg) * 2 + j) * 2048; \
        bf[(gg) * 2 + j][0] = *(const bf16x8*)(_p + kx0); \
        bf[(gg) * 2 + j][1] = *(const bf16x8*)(_p + kx1); \
    } } while (0)
#define MFQ(h, gg) do { \
    __builtin_amdgcn_s_setprio(1); \
    _Pragma("unroll") \
    for (int j = 0; j < 2; ++j) \
        _Pragma("unroll") \
        for (int ks = 0; ks < 2; ++ks) \
            _Pragma("unroll") \
            for (int mf = 0; mf < 4; ++mf) \
                acc[(h) * 4 + mf][(gg) * 2 + j] = __builtin_amdgcn_mfma_f32_16x16x32_bf16( \
                    bf[(gg) * 2 + j][ks], af[mf][ks], acc[(h) * 4 + mf][(gg) * 2 + j], 0, 0, 0); \
    __builtin_amdgcn_s_setprio(0); \
} while (0)

    #pragma unroll 2
    for (int t = 0; t < 16; ++t) {
        const unsigned cb = (unsigned)(t & 1) * 65536;
        // phase 0: stage next tile + A-half0 + B-half0
        if (t + 1 < 16) STAGE((t & 1) ^ 1, (t + 1) * 128);
        LDA(0);
        LDB(0);
        __builtin_amdgcn_s_barrier();
        MFQ(0, 0);
        // phase 1: B-half1
        LDB(1);
        __builtin_amdgcn_s_barrier();
        MFQ(0, 1);
        // phase 2: A-half1
        LDA(1);
        __builtin_amdgcn_s_barrier();
        MFQ(1, 1);
        // phase 3
        __builtin_amdgcn_s_barrier();
        MFQ(1, 0);
        // tile boundary: next tile's loads (issued at phase 0) must be done
        asm volatile("s_waitcnt vmcnt(0)" ::: "memory");
        __builtin_amdgcn_s_barrier();
        __builtin_amdgcn_sched_barrier(0);
    }
#undef LDA
#undef LDB
#undef MFQ
#undef STAGE

    // epilogue: bias + pack bf16 + 8B stores (4 consecutive vocab per lane)
    #pragma unroll
    for (int nf = 0; nf < 4; ++nf) {
        const int v = n0 + wn * 64 + nf * 16 + q * 4;
        float4 bv = *(const float4*)(bfc + v);
        #pragma unroll
        for (int mf8 = 0; mf8 < 8; ++mf8) {
            f32x4 a = acc[mf8][nf];
            uint2 pk;
            pk.x = (uint32_t)f2bf(a[0] + bv.x) | ((uint32_t)f2bf(a[1] + bv.y) << 16);
            pk.y = (uint32_t)f2bf(a[2] + bv.z) | ((uint32_t)f2bf(a[3] + bv.w) << 16);
            size_t m = R0 + (size_t)(wm * 128 + mf8 * 16 + lr);
            *(uint2*)(outb + m * 4096 + 2048 + (size_t)v * 2) = pk;
        }
    }
}

// ---------------- softmax/blank epilogue pass --------------------------------
__global__ __launch_bounds__(256) void k_softmax(char* __restrict__ outb)
{
    const int row = blockIdx.x * 4 + (threadIdx.x >> 6);
    const int l = threadIdx.x & 63;
    const char* lp = outb + (size_t)row * 4096 + 2048 + l * 32;
    uint4 wa = *(const uint4*)lp;
    uint4 wb = *(const uint4*)(lp + 16);
    float v[16];
    uint32_t wd[8] = { wa.x, wa.y, wa.z, wa.w, wb.x, wb.y, wb.z, wb.w };
    #pragma unroll
    for (int i = 0; i < 8; ++i) { v[2*i] = bf2f_lo(wd[i]); v[2*i+1] = bf2f_hi(wd[i]); }

    float l0 = __shfl(v[0], 0);
    float m = (l == 0) ? -3.0e38f : v[0];
    #pragma unroll
    for (int i = 1; i < 16; ++i) m = fmaxf(m, v[i]);
    #pragma unroll
    for (int s = 1; s < 64; s <<= 1) m = fmaxf(m, __shfl_xor(m, s));
    float s = (l == 0) ? 0.0f : __expf(v[0] - m);
    #pragma unroll
    for (int i = 1; i < 16; ++i) s += __expf(v[i] - m);
    #pragma unroll
    for (int sh = 1; sh < 64; sh <<= 1) s += __shfl_xor(s, sh);

    float lse = m + __logf(s);
    float fin = -lse - softplus_f(l0);     // log_sigmoid(-l0) - lse
    float f0v = -softplus_f(-l0);          // log_sigmoid(l0)

    float* op = (float*)(outb + (size_t)row * 4096) + l * 16;
    #pragma unroll
    for (int c = 0; c < 4; ++c) {
        float4 o;
        o.x = v[4*c+0] + fin; o.y = v[4*c+1] + fin;
        o.z = v[4*c+2] + fin; o.w = v[4*c+3] + fin;
        if (l == 0 && c == 0) o.x = f0v;
        *(float4*)(op + 4*c) = o;
    }
}

extern "C" void kernel_launch(void* const* d_in, const int* in_sizes, int n_in,
                              void* d_out, int out_size, void* d_ws, size_t ws_size,
                              hipStream_t stream)
{
    const float* encoder = (const float*)d_in[0]; // [4,400,512]
    const float* decoder = (const float*)d_in[1]; // [4,80,512]
    const float* W_enc   = (const float*)d_in[2]; // [1024,512]
    const float* b_enc   = (const float*)d_in[3]; // [1024]
    const float* W_dec   = (const float*)d_in[4]; // [1024,512]
    const float* b_dec   = (const float*)d_in[5]; // [1024]
    const float* W_fc    = (const float*)d_in[6]; // [1024,1024]
    const float* b_fc    = (const float*)d_in[7]; // [1024]
    char* outb = (char*)d_out;

    char* ws = (char*)d_ws;
    float*          enc_f  = (float*)(ws);                      // 1600*1024 f32
    float*          dec_f  = (float*)(ws + 6553600);            // 320*1024 f32
    unsigned short* Wfc_h  = (unsigned short*)(ws + 7864320);   // 1024*1024 bf16
    unsigned short* Wenc_h = (unsigned short*)(ws + 9961472);   // 1024*512 bf16
    unsigned short* Wdec_h = (unsigned short*)(ws + 11010048);  // 1024*512 bf16
    unsigned short* encI_h = (unsigned short*)(ws + 12058624);  // 1600*512 bf16
    unsigned short* decI_h = (unsigned short*)(ws + 13697024);  // 320*512 bf16

    const int nEnc = 4 * 400 * 512, nDec = 4 * 80 * 512;
    const int nWe = 1024 * 512, nWd = 1024 * 512, nWf = 1024 * 1024;
    const int totalF4 = (nEnc + nDec + nWe + nWd + nWf) >> 2;
    k_convert<<<(totalF4 + 255) / 256, 256, 0, stream>>>(
        encoder, decoder, W_enc, W_dec, W_fc,
        encI_h, decI_h, Wenc_h, Wdec_h, Wfc_h,
        nEnc, nDec, nWe, nWd, nWf);

    k_proj<<<dim3(1600 / 32, 8), 256, 0, stream>>>(encI_h, Wenc_h, b_enc, enc_f);
    k_proj<<<dim3(320 / 32, 8), 256, 0, stream>>>(decI_h, Wdec_h, b_dec, dec_f);

    k_tanhA<<<4096, 256, 0, stream>>>(enc_f, dec_f, outb);

    const int GEMM_SMEM = 131072;
    hipFuncSetAttribute(reinterpret_cast<const void*>(k_gemm),
                        hipFuncAttributeMaxDynamicSharedMemorySize, GEMM_SMEM);
    k_gemm<<<2000, 512, GEMM_SMEM, stream>>>(Wfc_h, b_fc, outb);

    k_softmax<<<32000, 256, 0, stream>>>(outb);
}

// Round 7
// 655.474 us; speedup vs baseline: 1.0640x; 1.0640x over previous
//
#include <hip/hip_runtime.h>
#include <hip/hip_bf16.h>
#include <cstdint>
#include <cstddef>

typedef short bf16x8 __attribute__((ext_vector_type(8)));
typedef float f32x4 __attribute__((ext_vector_type(4)));

static __device__ __forceinline__ unsigned short f2bf(float f) {
    union { float f; uint32_t u; } c; c.f = f;
    uint32_t r = c.u + 0x7FFFu + ((c.u >> 16) & 1u);
    return (unsigned short)(r >> 16);
}
static __device__ __forceinline__ float bf2f_lo(uint32_t w) {
    union { uint32_t u; float f; } c; c.u = w << 16; return c.f;
}
static __device__ __forceinline__ float bf2f_hi(uint32_t w) {
    union { uint32_t u; float f; } c; c.u = w & 0xffff0000u; return c.f;
}
static __device__ __forceinline__ float fast_tanh(float x) {
    float e = __expf(2.0f * x);
    return 1.0f - 2.0f / (e + 1.0f);
}
static __device__ __forceinline__ float softplus_f(float x) {
    return fmaxf(x, 0.0f) + log1pf(__expf(-fabsf(x)));
}

#define GLOAD_LDS16(g, l) \
    __builtin_amdgcn_global_load_lds((const __attribute__((address_space(1))) void*)(g), \
                                     (__attribute__((address_space(3))) void*)(l), 16, 0, 0)

// ---------------- f32 -> bf16 conversion, 5 segments in one launch ----------
__global__ __launch_bounds__(256) void k_convert(
    const float* __restrict__ s0, const float* __restrict__ s1,
    const float* __restrict__ s2, const float* __restrict__ s3,
    const float* __restrict__ s4,
    unsigned short* __restrict__ d0, unsigned short* __restrict__ d1,
    unsigned short* __restrict__ d2, unsigned short* __restrict__ d3,
    unsigned short* __restrict__ d4,
    int n0, int n1, int n2, int n3, int n4)
{
    int i = blockIdx.x * 256 + threadIdx.x; // float4 index
    int c0 = n0 >> 2, c1 = c0 + (n1 >> 2), c2 = c1 + (n2 >> 2),
        c3 = c2 + (n3 >> 2), c4 = c3 + (n4 >> 2);
    if (i >= c4) return;
    const float* s; unsigned short* d; int j;
    if (i < c0)      { s = s0; d = d0; j = i; }
    else if (i < c1) { s = s1; d = d1; j = i - c0; }
    else if (i < c2) { s = s2; d = d2; j = i - c1; }
    else if (i < c3) { s = s3; d = d3; j = i - c2; }
    else             { s = s4; d = d4; j = i - c3; }
    float4 v = reinterpret_cast<const float4*>(s)[j];
    ushort4 o;
    o.x = f2bf(v.x); o.y = f2bf(v.y); o.z = f2bf(v.z); o.w = f2bf(v.w);
    reinterpret_cast<ushort4*>(d)[j] = o;
}

// ---------------- projection GEMM: out[m,f] = sum_d A[m,d]*W[f,d] + bias[f] --
__global__ __launch_bounds__(256) void k_proj(
    const unsigned short* __restrict__ A,   // [M][512] bf16
    const unsigned short* __restrict__ W,   // [1024][512] bf16
    const float* __restrict__ bias,         // [1024]
    float* __restrict__ out)                // [M][1024] f32
{
    __shared__ unsigned short As[32 * 512];
    const int tid = threadIdx.x;
    const int m0 = blockIdx.x * 32;
    const int c0 = blockIdx.y * 128;
    {
        int row = tid >> 3;
        const unsigned short* src = A + (size_t)(m0 + row) * 512;
        unsigned int base = row * 1024;
        unsigned int sw = (row & 7) << 4;
        #pragma unroll
        for (int c = 0; c < 8; ++c) {
            int col = (tid & 7) * 8 + c * 64;
            bf16x8 v = *reinterpret_cast<const bf16x8*>(src + col);
            *reinterpret_cast<bf16x8*>(
                reinterpret_cast<char*>(As) + ((base + col * 2) ^ sw)) = v;
        }
    }
    __syncthreads();
    const int w = tid >> 6, l = tid & 63;
    const int lr = l & 15, lkb = (l >> 4) * 8;
    f32x4 acc[2][2] = {};
    const int colbase = c0 + w * 32;
    const unsigned short* Wb = W + (size_t)(colbase + lr) * 512 + lkb;
    const unsigned int sw = (lr & 7) << 4;
    for (int ks = 0; ks < 16; ++ks) {
        unsigned int kb = (ks * 32 + lkb) * 2;
        bf16x8 a0 = *reinterpret_cast<const bf16x8*>(
            reinterpret_cast<const char*>(As) + ((lr * 1024 + kb) ^ sw));
        bf16x8 a1 = *reinterpret_cast<const bf16x8*>(
            reinterpret_cast<const char*>(As) + (((16 + lr) * 1024 + kb) ^ sw));
        #pragma unroll
        for (int nf = 0; nf < 2; ++nf) {
            bf16x8 b = *reinterpret_cast<const bf16x8*>(Wb + nf * 16 * 512 + ks * 32);
            acc[0][nf] = __builtin_amdgcn_mfma_f32_16x16x32_bf16(a0, b, acc[0][nf], 0, 0, 0);
            acc[1][nf] = __builtin_amdgcn_mfma_f32_16x16x32_bf16(a1, b, acc[1][nf], 0, 0, 0);
        }
    }
    const int qr = (l >> 4) * 4;
    #pragma unroll
    for (int nf = 0; nf < 2; ++nf) {
        int col = colbase + nf * 16 + lr;
        float bv = bias[col];
        #pragma unroll
        for (int mf = 0; mf < 2; ++mf)
            #pragma unroll
            for (int r = 0; r < 4; ++r)
                out[(size_t)(m0 + mf * 16 + qr + r) * 1024 + col] = acc[mf][nf][r] + bv;
    }
}

// ---------------- A = tanh(enc+dec) -> bf16, interleaved into out -----------
// Row r of out (4096 B): bytes [0,2048) hold A[r][0..1023] bf16.
__global__ __launch_bounds__(256) void k_tanhA(
    const float* __restrict__ enc_f,   // [1600][1024]
    const float* __restrict__ dec_f,   // [320][1024]
    char* __restrict__ outb)
{
    const int NG = 128000 * 128;       // 16B groups
    for (int g = blockIdx.x * 256 + threadIdx.x; g < NG; g += gridDim.x * 256) {
        int row = g >> 7, c8 = g & 127;
        int bt = row / 80;
        int u = row - bt * 80;
        int b = bt / 400;
        const float* ep = enc_f + (size_t)bt * 1024 + c8 * 8;
        const float* dp = dec_f + (size_t)(b * 80 + u) * 1024 + c8 * 8;
        float4 e0 = *(const float4*)ep, e1 = *(const float4*)(ep + 4);
        float4 f0 = *(const float4*)dp, f1 = *(const float4*)(dp + 4);
        uint4 pk;
        pk.x = (uint32_t)f2bf(fast_tanh(e0.x + f0.x)) | ((uint32_t)f2bf(fast_tanh(e0.y + f0.y)) << 16);
        pk.y = (uint32_t)f2bf(fast_tanh(e0.z + f0.z)) | ((uint32_t)f2bf(fast_tanh(e0.w + f0.w)) << 16);
        pk.z = (uint32_t)f2bf(fast_tanh(e1.x + f1.x)) | ((uint32_t)f2bf(fast_tanh(e1.y + f1.y)) << 16);
        pk.w = (uint32_t)f2bf(fast_tanh(e1.z + f1.z)) | ((uint32_t)f2bf(fast_tanh(e1.w + f1.w)) << 16);
        *(uint4*)(outb + (size_t)row * 4096 + c8 * 16) = pk;
    }
}

// ---------------- main GEMM: logits = A @ Wfc^T + bias (bf16 out) -----------
// 256x256 tile, BK=64, 512 thr (8 waves: wm 2 x wn 4), 2x64KB LDS dbuf.
// Counted-vmcnt pipeline (T3+T4): loads for tile T issued 2-per-phase from
// tile T-2 phase 3 through tile T-1 phase 2; boundary waits vmcnt(2) (the 2
// newest = next-next tile's A0/A2 stay in flight). Phase-3 staging limited to
// A-chunks 0/2 (reads completed by phase 0) so in-flight phase-2 ds_reads of
// chunks 1/3 are never overwritten. XOR-swizzled LDS, pre-swizzled sources.
__global__ __launch_bounds__(512, 1) void k_gemm(
    const unsigned short* __restrict__ Wfc,   // [1024][1024] bf16
    const float* __restrict__ bfc,            // [1024]
    char* __restrict__ outb)                  // A in [0,2048), logits out [2048,4096)
{
    extern __shared__ char smem[];            // 2 x (32KB A + 32KB B)
    const int tid = threadIdx.x;
    const int w = tid >> 6, l = tid & 63;
    const int lr = l & 15, q = l >> 4;
    const int wm = w >> 2, wn = w & 3;

    // grid 2000 = 8 XCDs x 250; within XCD: np fastest (4 N-panels share A)
    const int bid = (int)blockIdx.x;
    const int g = (bid & 7) * 250 + (bid >> 3);
    const size_t R0 = (size_t)(g >> 2) * 256;
    const int n0 = (g & 3) * 256;

    // staging source (pre-swizzled): dest d = tid*16 + i*8192 (linear),
    // logical L = d ^ (((d>>7)&7)<<4); row = tid>>3 + i*64, kb = L&127
    const unsigned kb0 = (unsigned)(((tid & 7) * 16) ^ (((tid >> 3) & 7) << 4));
    const int row0 = tid >> 3;
    const char* sA = outb + (R0 + row0) * 4096 + kb0;
    const char* sB = (const char*)Wfc + (size_t)(n0 + row0) * 2048 + kb0;
    char* const dbase = smem + tid * 16;

    // chunk map (per-thread 16B each): A0:+0, A1:+8192, A2:+16384, A3:+24576,
    //                                  B0:+32768, B1:+40960, B2:+49152, B3:+57344
#define STG_ALL8(buf, T) do { \
    const char* _a = sA + (T) * 128; const char* _b = sB + (T) * 128; \
    char* _d = dbase + (buf); \
    GLOAD_LDS16(_a,          _d);          \
    GLOAD_LDS16(_a + 262144, _d + 8192);   \
    GLOAD_LDS16(_a + 524288, _d + 16384);  \
    GLOAD_LDS16(_a + 786432, _d + 24576);  \
    GLOAD_LDS16(_b,          _d + 32768);  \
    GLOAD_LDS16(_b + 131072, _d + 40960);  \
    GLOAD_LDS16(_b + 262144, _d + 49152);  \
    GLOAD_LDS16(_b + 393216, _d + 57344);  \
} while (0)
#define STG_A13(buf, T) do { const char* _a = sA + (T) * 128; char* _d = dbase + (buf); \
    GLOAD_LDS16(_a + 262144, _d + 8192); GLOAD_LDS16(_a + 786432, _d + 24576); } while (0)
#define STG_B01(buf, T) do { const char* _b = sB + (T) * 128; char* _d = dbase + (buf); \
    GLOAD_LDS16(_b,          _d + 32768); GLOAD_LDS16(_b + 131072, _d + 40960); } while (0)
#define STG_B23(buf, T) do { const char* _b = sB + (T) * 128; char* _d = dbase + (buf); \
    GLOAD_LDS16(_b + 262144, _d + 49152); GLOAD_LDS16(_b + 393216, _d + 57344); } while (0)
#define STG_A02(buf, T) do { const char* _a = sA + (T) * 128; char* _d = dbase + (buf); \
    GLOAD_LDS16(_a,          _d);         GLOAD_LDS16(_a + 524288, _d + 16384); } while (0)

    // fragment read offsets
    const unsigned key = (unsigned)((lr & 7) << 4);
    const unsigned kx0 = (unsigned)(q * 16) ^ key;
    const unsigned kx1 = (unsigned)(q * 16 + 64) ^ key;
    const unsigned abase = (unsigned)((wm * 128 + lr) * 128);           // + h*8192 + mf*2048
    const unsigned bbase = (unsigned)(32768 + (wn * 64 + lr) * 128);    // + nf*2048

    f32x4 acc[8][4] = {};
    bf16x8 af[4][2], bf[4][2];

#define LDA(h) do { \
    _Pragma("unroll") \
    for (int mf = 0; mf < 4; ++mf) { \
        const char* _p = smem + cb + abase + (h) * 8192 + mf * 2048; \
        af[mf][0] = *(const bf16x8*)(_p + kx0); \
        af[mf][1] = *(const bf16x8*)(_p + kx1); \
    } } while (0)
#define LDB(gg) do { \
    _Pragma("unroll") \
    for (int j = 0; j < 2; ++j) { \
        const char* _p = smem + cb + bbase + ((gg) * 2 + j) * 2048; \
        bf[(gg) * 2 + j][0] = *(const bf16x8*)(_p + kx0); \
        bf[(gg) * 2 + j][1] = *(const bf16x8*)(_p + kx1); \
    } } while (0)
#define MFQ(h, gg) do { \
    __builtin_amdgcn_s_setprio(1); \
    _Pragma("unroll") \
    for (int j = 0; j < 2; ++j) \
        _Pragma("unroll") \
        for (int ks = 0; ks < 2; ++ks) \
            _Pragma("unroll") \
            for (int mf = 0; mf < 4; ++mf) \
                acc[(h) * 4 + mf][(gg) * 2 + j] = __builtin_amdgcn_mfma_f32_16x16x32_bf16( \
                    bf[(gg) * 2 + j][ks], af[mf][ks], acc[(h) * 4 + mf][(gg) * 2 + j], 0, 0, 0); \
    __builtin_amdgcn_s_setprio(0); \
} while (0)
#define BAR __builtin_amdgcn_s_barrier()

    // prologue: tile0 all 8 (buf0), then tile1 A0/A2 (buf1) as the 2 newest
    STG_ALL8(0u, 0);
    STG_A02(65536u, 1);
    asm volatile("s_waitcnt vmcnt(2)" ::: "memory");
    BAR;
    __builtin_amdgcn_sched_barrier(0);

    #pragma unroll 2
    for (int t = 0; t < 16; ++t) {
        const unsigned cb = (unsigned)(t & 1) * 65536u;
        const unsigned nb = cb ^ 65536u;
        const bool s1 = (t + 1 < 16), s2 = (t + 2 < 16);
        // phase 0
        LDA(0); LDB(0);
        if (s1) STG_A13(nb, t + 1);
        BAR;
        MFQ(0, 0);
        // phase 1
        LDB(1);
        if (s1) STG_B01(nb, t + 1);
        BAR;
        MFQ(0, 1);
        // phase 2
        LDA(1);
        if (s1) STG_B23(nb, t + 1);
        BAR;
        MFQ(1, 1);
        // phase 3 (A0/A2 of cur buf fully read since phase 0 -> safe to overwrite)
        if (s2) STG_A02(cb, t + 2);
        BAR;
        MFQ(1, 0);
        // boundary: counted wait -- keep the 2 newest (t+2's A0/A2) in flight
        if (t < 14) {
            asm volatile("s_waitcnt vmcnt(2)" ::: "memory");
            BAR;
            __builtin_amdgcn_sched_barrier(0);
        } else if (t == 14) {
            asm volatile("s_waitcnt vmcnt(0)" ::: "memory");
            BAR;
            __builtin_amdgcn_sched_barrier(0);
        }
    }
#undef LDA
#undef LDB
#undef MFQ
#undef BAR
#undef STG_ALL8
#undef STG_A13
#undef STG_B01
#undef STG_B23
#undef STG_A02

    // epilogue: bias + pack bf16 + 8B stores (4 consecutive vocab per lane)
    #pragma unroll
    for (int nf = 0; nf < 4; ++nf) {
        const int v = n0 + wn * 64 + nf * 16 + q * 4;
        float4 bv = *(const float4*)(bfc + v);
        #pragma unroll
        for (int mf8 = 0; mf8 < 8; ++mf8) {
            f32x4 a = acc[mf8][nf];
            uint2 pk;
            pk.x = (uint32_t)f2bf(a[0] + bv.x) | ((uint32_t)f2bf(a[1] + bv.y) << 16);
            pk.y = (uint32_t)f2bf(a[2] + bv.z) | ((uint32_t)f2bf(a[3] + bv.w) << 16);
            size_t m = R0 + (size_t)(wm * 128 + mf8 * 16 + lr);
            *(uint2*)(outb + m * 4096 + 2048 + (size_t)v * 2) = pk;
        }
    }
}

// ---------------- softmax/blank epilogue pass --------------------------------
__global__ __launch_bounds__(256) void k_softmax(char* __restrict__ outb)
{
    const int row = blockIdx.x * 4 + (threadIdx.x >> 6);
    const int l = threadIdx.x & 63;
    const char* lp = outb + (size_t)row * 4096 + 2048 + l * 32;
    uint4 wa = *(const uint4*)lp;
    uint4 wb = *(const uint4*)(lp + 16);
    float v[16];
    uint32_t wd[8] = { wa.x, wa.y, wa.z, wa.w, wb.x, wb.y, wb.z, wb.w };
    #pragma unroll
    for (int i = 0; i < 8; ++i) { v[2*i] = bf2f_lo(wd[i]); v[2*i+1] = bf2f_hi(wd[i]); }

    float l0 = __shfl(v[0], 0);
    float m = (l == 0) ? -3.0e38f : v[0];
    #pragma unroll
    for (int i = 1; i < 16; ++i) m = fmaxf(m, v[i]);
    #pragma unroll
    for (int s = 1; s < 64; s <<= 1) m = fmaxf(m, __shfl_xor(m, s));
    float s = (l == 0) ? 0.0f : __expf(v[0] - m);
    #pragma unroll
    for (int i = 1; i < 16; ++i) s += __expf(v[i] - m);
    #pragma unroll
    for (int sh = 1; sh < 64; sh <<= 1) s += __shfl_xor(s, sh);

    float lse = m + __logf(s);
    float fin = -lse - softplus_f(l0);     // log_sigmoid(-l0) - lse
    float f0v = -softplus_f(-l0);          // log_sigmoid(l0)

    float* op = (float*)(outb + (size_t)row * 4096) + l * 16;
    #pragma unroll
    for (int c = 0; c < 4; ++c) {
        float4 o;
        o.x = v[4*c+0] + fin; o.y = v[4*c+1] + fin;
        o.z = v[4*c+2] + fin; o.w = v[4*c+3] + fin;
        if (l == 0 && c == 0) o.x = f0v;
        *(float4*)(op + 4*c) = o;
    }
}

extern "C" void kernel_launch(void* const* d_in, const int* in_sizes, int n_in,
                              void* d_out, int out_size, void* d_ws, size_t ws_size,
                              hipStream_t stream)
{
    const float* encoder = (const float*)d_in[0]; // [4,400,512]
    const float* decoder = (const float*)d_in[1]; // [4,80,512]
    const float* W_enc   = (const float*)d_in[2]; // [1024,512]
    const float* b_enc   = (const float*)d_in[3]; // [1024]
    const float* W_dec   = (const float*)d_in[4]; // [1024,512]
    const float* b_dec   = (const float*)d_in[5]; // [1024]
    const float* W_fc    = (const float*)d_in[6]; // [1024,1024]
    const float* b_fc    = (const float*)d_in[7]; // [1024]
    char* outb = (char*)d_out;

    char* ws = (char*)d_ws;
    float*          enc_f  = (float*)(ws);                      // 1600*1024 f32
    float*          dec_f  = (float*)(ws + 6553600);            // 320*1024 f32
    unsigned short* Wfc_h  = (unsigned short*)(ws + 7864320);   // 1024*1024 bf16
    unsigned short* Wenc_h = (unsigned short*)(ws + 9961472);   // 1024*512 bf16
    unsigned short* Wdec_h = (unsigned short*)(ws + 11010048);  // 1024*512 bf16
    unsigned short* encI_h = (unsigned short*)(ws + 12058624);  // 1600*512 bf16
    unsigned short* decI_h = (unsigned short*)(ws + 13697024);  // 320*512 bf16

    const int nEnc = 4 * 400 * 512, nDec = 4 * 80 * 512;
    const int nWe = 1024 * 512, nWd = 1024 * 512, nWf = 1024 * 1024;
    const int totalF4 = (nEnc + nDec + nWe + nWd + nWf) >> 2;
    k_convert<<<(totalF4 + 255) / 256, 256, 0, stream>>>(
        encoder, decoder, W_enc, W_dec, W_fc,
        encI_h, decI_h, Wenc_h, Wdec_h, Wfc_h,
        nEnc, nDec, nWe, nWd, nWf);

    k_proj<<<dim3(1600 / 32, 8), 256, 0, stream>>>(encI_h, Wenc_h, b_enc, enc_f);
    k_proj<<<dim3(320 / 32, 8), 256, 0, stream>>>(decI_h, Wdec_h, b_dec, dec_f);

    k_tanhA<<<4096, 256, 0, stream>>>(enc_f, dec_f, outb);

    const int GEMM_SMEM = 131072;
    hipFuncSetAttribute(reinterpret_cast<const void*>(k_gemm),
                        hipFuncAttributeMaxDynamicSharedMemorySize, GEMM_SMEM);
    k_gemm<<<2000, 512, GEMM_SMEM, stream>>>(Wfc_h, b_fc, outb);

    k_softmax<<<32000, 256, 0, stream>>>(outb);
}